// Round 3
// baseline (458.525 us; speedup 1.0000x reference)
//
#include <hip/hip_runtime.h>
#include <math.h>

#define D_MODEL   512
#define MAX_PL    32
#define TGT       4
#define G_TILES   32
#define HSTRIDE   65
#define NTHREADS  256

// Block = 256 threads; two blocks per tile-group: half h covers dims
// [h*256, h*256+255], one dim per thread. Per-thread w_emb rows for all 3
// tables = 56 VGPRs; x read in 8/16-float chunks so peak live stays well
// under the 128-VGPR cap of __launch_bounds__(256,4) -> 4 waves/SIMD.
// Each tile-group = 32 consecutive (n,r) tiles = one full n (r=0..31), so PE
// positions start at 0 for every group. PE advanced by a per-lane
// sign-adjusted rotation recurrence, re-seeded from sincosf every 8 tiles
// (max 32 recurrence steps -> drift < 4e-6).
__global__ __launch_bounds__(NTHREADS, 4)
void ape_main(const float* __restrict__ x,
              const float* __restrict__ w1, const float* __restrict__ b1,
              const float* __restrict__ w2, const float* __restrict__ b2,
              const float* __restrict__ we0, const float* __restrict__ we1,
              const float* __restrict__ we2,
              float* __restrict__ out)
{
    __shared__ float xs[G_TILES * MAX_PL];     // 32 tiles x 32 samples (4 KB)
    __shared__ float hbuf[G_TILES * HSTRIDE];  // hidden acts, padded stride 65
    __shared__ int   preds[G_TILES];

    const int t     = threadIdx.x;
    const int group = blockIdx.x >> 1;
    const int half  = blockIdx.x & 1;
    const long long tile0 = (long long)group * G_TILES;

    // ---- stage x (contiguous: tile nr starts at nr*32) ----
    {
        const float* xb = x + tile0 * MAX_PL;
        #pragma unroll
        for (int i = 0; i < 4; ++i)
            xs[t + i * 256] = xb[t + i * 256];
    }
    __syncthreads();

    // ---- hidden layer: h = relu(xr @ w1^T + b1), 32 tiles x 64 units ----
    // (duplicated across the two half-blocks of a group; ~256 FMAs, cheap)
    {
        const int hidx = t & 63;
        float wreg[MAX_PL] __attribute__((aligned(16)));
        {
            const float4* w1q = (const float4*)(w1 + hidx * MAX_PL);
            float4* wq = (float4*)wreg;
            #pragma unroll
            for (int i = 0; i < 8; ++i) wq[i] = w1q[i];
        }
        const float bb = b1[hidx];
        const int gbase = t >> 6;
        #pragma unroll
        for (int gg = 0; gg < 8; ++gg) {
            const int g = gbase + gg * 4;
            float acc = 0.f;
            #pragma unroll
            for (int p = 0; p < MAX_PL; ++p)
                acc = fmaf(wreg[p], xs[g * MAX_PL + p], acc);
            acc += bb;
            hbuf[g * HSTRIDE + hidx] = fmaxf(acc, 0.f);
        }
    }
    __syncthreads();

    // ---- logits + argmax fused: one thread per tile (t < 32, wave 0) ----
    // stride-65 rows -> lanes hit distinct banks: conflict-free.
    if (t < G_TILES) {
        const float* hg = hbuf + t * HSTRIDE;
        float l[3];
        #pragma unroll
        for (int e = 0; e < 3; ++e) {
            const float* w2r = w2 + e * 64;
            float acc = 0.f;
            #pragma unroll 8
            for (int h = 0; h < 64; ++h) acc = fmaf(w2r[h], hg[h], acc);
            l[e] = acc + b2[e];
        }
        int bi = 0; float best = l[0];
        if (l[1] > best) { best = l[1]; bi = 1; }
        if (l[2] > best) { bi = 2; }
        preds[t] = bi;
    }

    // ---- preload this thread's w_emb row (dim d) for all 3 tables ----
    const int d = half * 256 + t;
    float r0[8]  __attribute__((aligned(16)));
    float r1[16] __attribute__((aligned(16)));
    float r2[32] __attribute__((aligned(16)));
    {
        const float4* s0 = (const float4*)(we0 + (size_t)d * 8);
        float4* q0 = (float4*)r0;
        #pragma unroll
        for (int i = 0; i < 2; ++i) q0[i] = s0[i];
        const float4* s1 = (const float4*)(we1 + (size_t)d * 16);
        float4* q1 = (float4*)r1;
        #pragma unroll
        for (int i = 0; i < 4; ++i) q1[i] = s1[i];
        const float4* s2 = (const float4*)(we2 + (size_t)d * 32);
        float4* q2 = (float4*)r2;
        #pragma unroll
        for (int i = 0; i < 8; ++i) q2[i] = s2[i];
    }

    // ---- PE state: p = value to add (sin for even d, cos for odd d) ----
    // Rotation by angle freq per position; odd lanes rotate with -s1r so the
    // same two FMAs advance both variants (p,q) = even ? (s,c) : (c,s).
    const int   dpair = d & ~1;
    const float freq  = expf((float)dpair * -0.017988946f);  // -ln(10000)/512
    float s1r, c1r;
    sincosf(freq, &s1r, &c1r);
    const float s1l = (d & 1) ? -s1r : s1r;
    float pg = (d & 1) ? 1.f : 0.f;   // position 0: sin0=0 / cos0=1
    float qg = (d & 1) ? 0.f : 1.f;

    __syncthreads();

    // ---- per-tile embedding + PE + store ----
    for (int g = 0; g < G_TILES; ++g) {
        // re-seed rotation every 8 tiles: caps recurrence drift at 32 steps
        if ((g & 7) == 0 && g != 0) {
            float sv, cv;
            sincosf(freq * (float)(4 * g), &sv, &cv);
            pg = (d & 1) ? cv : sv;
            qg = (d & 1) ? sv : cv;
        }
        const int pred = preds[g];
        float* obase = out + (tile0 + g) * (TGT * D_MODEL) + d;
        const float4* xg4 = (const float4*)(xs + g * MAX_PL);

        float v[TGT];
        if (pred == 0) {            // pl=8: 4 distinct patches
            #pragma unroll
            for (int k = 0; k < 4; ++k) {
                float xq8[8] __attribute__((aligned(16)));
                ((float4*)xq8)[0] = xg4[2 * k];
                ((float4*)xq8)[1] = xg4[2 * k + 1];
                float a = 0.f;
                #pragma unroll
                for (int j = 0; j < 8; ++j)
                    a = fmaf(r0[j], xq8[j], a);
                v[k] = a;
            }
        } else if (pred == 1) {     // pl=16: repeat idx [0,0,0,1]
            float bt[2];
            #pragma unroll
            for (int kp = 0; kp < 2; ++kp) {
                float xq16[16] __attribute__((aligned(16)));
                #pragma unroll
                for (int i = 0; i < 4; ++i)
                    ((float4*)xq16)[i] = xg4[kp * 4 + i];
                float a = 0.f;
                #pragma unroll
                for (int j = 0; j < 16; ++j)
                    a = fmaf(r1[j], xq16[j], a);
                bt[kp] = a;
            }
            v[0] = bt[0]; v[1] = bt[0]; v[2] = bt[0]; v[3] = bt[1];
        } else {                    // pl=32: one patch, repeated 4x
            float a = 0.f;
            #pragma unroll
            for (int c = 0; c < 4; ++c) {
                float xq8[8] __attribute__((aligned(16)));
                ((float4*)xq8)[0] = xg4[2 * c];
                ((float4*)xq8)[1] = xg4[2 * c + 1];
                #pragma unroll
                for (int j = 0; j < 8; ++j)
                    a = fmaf(r2[c * 8 + j], xq8[j], a);
            }
            #pragma unroll
            for (int k = 0; k < 4; ++k) v[k] = a;
        }

        // k-loop: add PE, rotate (pg,qg) by freq per position; streaming store
        #pragma unroll
        for (int k = 0; k < 4; ++k) {
            __builtin_nontemporal_store(v[k] + pg, obase + k * D_MODEL);
            const float np = fmaf(pg, c1r,  qg * s1l);
            const float nq = fmaf(qg, c1r, -pg * s1l);
            pg = np; qg = nq;
        }
        // (pg,qg) now at position 4(g+1): carried into next tile (or re-seeded)
    }
}

// Second tuple output: the scalar C (=21) appended after x_patch.
__global__ void ape_tail(float* p, int n) {
    int i = blockIdx.x * blockDim.x + threadIdx.x;
    if (i < n) p[i] = 21.0f;
}

extern "C" void kernel_launch(void* const* d_in, const int* in_sizes, int n_in,
                              void* d_out, int out_size, void* d_ws, size_t ws_size,
                              hipStream_t stream)
{
    const float* x   = (const float*)d_in[0];
    const float* w1  = (const float*)d_in[1];
    const float* b1  = (const float*)d_in[2];
    const float* w2  = (const float*)d_in[3];
    const float* b2  = (const float*)d_in[4];
    const float* we0 = (const float*)d_in[5];
    const float* we1 = (const float*)d_in[6];
    const float* we2 = (const float*)d_in[7];
    float* out = (float*)d_out;

    const long long NR = (long long)in_sizes[0] / MAX_PL;   // B*C*R = 43008
    const int nblocks = (int)(NR / G_TILES) * 2;            // 2688 half-blocks
    ape_main<<<nblocks, NTHREADS, 0, stream>>>(x, w1, b1, w2, b2, we0, we1, we2, out);

    const long long main_elems = NR * (long long)(TGT * D_MODEL);
    if ((long long)out_size > main_elems) {
        const int tail = (int)((long long)out_size - main_elems);
        ape_tail<<<(tail + 63) / 64, 64, 0, stream>>>(out + main_elems, tail);
    }
}

// Round 4
// 379.936 us; speedup vs baseline: 1.2068x; 1.2068x over previous
//
#include <hip/hip_runtime.h>
#include <math.h>

#define D_MODEL   512
#define MAX_PL    32
#define TGT       4
#define NTHREADS  256
#define HSTRIDE   65

// ================= Kernel P: patch-length classifier =================
// Block: 256 threads, 64 tiles. Writes pred (0/1/2) per tile to workspace.
// Total work is trivial (~96M MAC device-wide): a few microseconds.
#define P_TILES 64
__global__ __launch_bounds__(NTHREADS)
void ape_preds(const float* __restrict__ x,
               const float* __restrict__ w1, const float* __restrict__ b1,
               const float* __restrict__ w2, const float* __restrict__ b2,
               int* __restrict__ preds_out)
{
    __shared__ float xs[P_TILES * MAX_PL];     // 8 KB
    __shared__ float hbuf[P_TILES * HSTRIDE];  // 16.6 KB, padded stride
    __shared__ float lbuf[P_TILES * 3];

    const int t = threadIdx.x;
    const long long tile0 = (long long)blockIdx.x * P_TILES;

    // stage x (contiguous)
    {
        const float* xb = x + tile0 * MAX_PL;
        #pragma unroll
        for (int i = 0; i < 8; ++i)
            xs[t + i * 256] = xb[t + i * 256];
    }
    __syncthreads();

    // hidden: h = relu(xr @ w1^T + b1); thread (hidx=t&63) x 16 tiles
    {
        const int hidx = t & 63;
        float wreg[MAX_PL] __attribute__((aligned(16)));
        {
            const float4* w1q = (const float4*)(w1 + hidx * MAX_PL);
            float4* wq = (float4*)wreg;
            #pragma unroll
            for (int i = 0; i < 8; ++i) wq[i] = w1q[i];
        }
        const float bb = b1[hidx];
        const int gbase = t >> 6;
        #pragma unroll
        for (int gg = 0; gg < 16; ++gg) {
            const int g = gbase + gg * 4;
            float acc = 0.f;
            #pragma unroll
            for (int p = 0; p < MAX_PL; ++p)
                acc = fmaf(wreg[p], xs[g * MAX_PL + p], acc);
            hbuf[g * HSTRIDE + hidx] = fmaxf(acc + bb, 0.f);
        }
    }
    __syncthreads();

    // logits: 192 threads (tile g = t/3, expert e = t%3)
    if (t < 192) {
        const int g = t / 3, e = t - g * 3;
        const float* hg = hbuf + g * HSTRIDE;
        const float* w2r = w2 + e * 64;
        float acc = 0.f;
        #pragma unroll 8
        for (int h = 0; h < 64; ++h) acc = fmaf(w2r[h], hg[h], acc);
        lbuf[g * 3 + e] = acc + b2[e];
    }
    __syncthreads();

    // argmax (first-max-on-ties, matching jnp.argmax) + store
    if (t < P_TILES) {
        const float l0 = lbuf[t * 3], l1 = lbuf[t * 3 + 1], l2 = lbuf[t * 3 + 2];
        int bi = 0; float best = l0;
        if (l1 > best) { best = l1; bi = 1; }
        if (l2 > best) { bi = 2; }
        preds_out[tile0 + t] = bi;
    }
}

// ================= Kernel E: embedding + PE + store =================
// Two blocks per tile-group (group = bid>>1, half = bid&1); half h covers
// dims [h*256, h*256+255], one dim per thread. No MLP/logits here: stage
// 4 KB x + 32 preds, ONE barrier, then pure streaming. Per-thread state:
// 56 table floats + 8-float x chunk + PE state ~ 95 VGPR -> 4 waves/SIMD.
// launch_bounds(256,3) caps at ~168 VGPR: no spill pressure, occupancy set
// by actual allocation.
#define G_TILES 32
__global__ __launch_bounds__(NTHREADS, 3)
void ape_embed(const float* __restrict__ x,
               const int* __restrict__ preds_in,
               const float* __restrict__ we0, const float* __restrict__ we1,
               const float* __restrict__ we2,
               float* __restrict__ out)
{
    __shared__ float xs[G_TILES * MAX_PL];   // 4 KB
    __shared__ int   sp[G_TILES];

    const int t     = threadIdx.x;
    const int group = blockIdx.x >> 1;
    const int half  = blockIdx.x & 1;
    const long long tile0 = (long long)group * G_TILES;

    // stage x + preds
    {
        const float* xb = x + tile0 * MAX_PL;
        #pragma unroll
        for (int i = 0; i < 4; ++i)
            xs[t + i * 256] = xb[t + i * 256];
        if (t < G_TILES) sp[t] = preds_in[tile0 + t];
    }

    // preload this thread's w_emb row (dim d) for all 3 tables (56 floats)
    const int d = half * 256 + t;
    float r0[8]  __attribute__((aligned(16)));
    float r1[16] __attribute__((aligned(16)));
    float r2[32] __attribute__((aligned(16)));
    {
        const float4* s0 = (const float4*)(we0 + (size_t)d * 8);
        ((float4*)r0)[0] = s0[0]; ((float4*)r0)[1] = s0[1];
        const float4* s1 = (const float4*)(we1 + (size_t)d * 16);
        #pragma unroll
        for (int i = 0; i < 4; ++i) ((float4*)r1)[i] = s1[i];
        const float4* s2 = (const float4*)(we2 + (size_t)d * 32);
        #pragma unroll
        for (int i = 0; i < 8; ++i) ((float4*)r2)[i] = s2[i];
    }

    // PE state: add sin(pos*freq) for even d, cos for odd d.
    // (pg,qg) rotated by freq per position; seed (ps,qs) advanced by a
    // precomputed 32-position rotation every 8 tiles (drift <= 36 steps).
    const float freq = expf((float)(d & ~1) * -0.017988946f);  // -ln(1e4)/512
    float s1r, c1r, s32r, c32r;
    sincosf(freq, &s1r, &c1r);
    sincosf(32.0f * freq, &s32r, &c32r);
    const float sgn  = (d & 1) ? -1.f : 1.f;
    const float s1l  = sgn * s1r;
    const float s32l = sgn * s32r;
    float ps = (d & 1) ? 1.f : 0.f;   // position 0: sin0=0 / cos0=1
    float qs = (d & 1) ? 0.f : 1.f;
    float pg = ps, qg = qs;

    __syncthreads();

    for (int g = 0; g < G_TILES; ++g) {
        if ((g & 7) == 0 && g != 0) {
            // advance seed exactly one 32-position step; re-seed inner state
            const float np = fmaf(ps, c32r,  qs * s32l);
            const float nq = fmaf(qs, c32r, -ps * s32l);
            ps = np; qs = nq;
            pg = ps; qg = qs;
        }
        const int pred = sp[g];
        float* obase = out + (tile0 + g) * (TGT * D_MODEL) + d;
        const float4* xg4 = (const float4*)(xs + g * MAX_PL);

        float v[TGT];
        if (pred == 0) {            // pl=8: 4 distinct patches
            #pragma unroll
            for (int k = 0; k < 4; ++k) {
                float xq8[8] __attribute__((aligned(16)));
                ((float4*)xq8)[0] = xg4[2 * k];
                ((float4*)xq8)[1] = xg4[2 * k + 1];
                float a = 0.f, b = 0.f;
                #pragma unroll
                for (int j = 0; j < 4; ++j) {
                    a = fmaf(r0[j],     xq8[j],     a);
                    b = fmaf(r0[j + 4], xq8[j + 4], b);
                }
                v[k] = a + b;
            }
        } else if (pred == 1) {     // pl=16: repeat idx [0,0,0,1]
            float bt[2];
            #pragma unroll
            for (int kp = 0; kp < 2; ++kp) {
                float a = 0.f, b = 0.f;
                #pragma unroll
                for (int c = 0; c < 2; ++c) {
                    float xq8[8] __attribute__((aligned(16)));
                    ((float4*)xq8)[0] = xg4[kp * 4 + 2 * c];
                    ((float4*)xq8)[1] = xg4[kp * 4 + 2 * c + 1];
                    #pragma unroll
                    for (int j = 0; j < 4; ++j) {
                        a = fmaf(r1[c * 8 + j],     xq8[j],     a);
                        b = fmaf(r1[c * 8 + j + 4], xq8[j + 4], b);
                    }
                }
                bt[kp] = a + b;
            }
            v[0] = bt[0]; v[1] = bt[0]; v[2] = bt[0]; v[3] = bt[1];
        } else {                    // pl=32: one patch, repeated 4x
            float a = 0.f, b = 0.f;
            #pragma unroll
            for (int c = 0; c < 4; ++c) {
                float xq8[8] __attribute__((aligned(16)));
                ((float4*)xq8)[0] = xg4[2 * c];
                ((float4*)xq8)[1] = xg4[2 * c + 1];
                #pragma unroll
                for (int j = 0; j < 4; ++j) {
                    a = fmaf(r2[c * 8 + j],     xq8[j],     a);
                    b = fmaf(r2[c * 8 + j + 4], xq8[j + 4], b);
                }
            }
            const float av = a + b;
            #pragma unroll
            for (int k = 0; k < 4; ++k) v[k] = av;
        }

        // add PE, rotate per position, nontemporal coalesced stores
        #pragma unroll
        for (int k = 0; k < 4; ++k) {
            __builtin_nontemporal_store(v[k] + pg, obase + k * D_MODEL);
            const float np = fmaf(pg, c1r,  qg * s1l);
            const float nq = fmaf(qg, c1r, -pg * s1l);
            pg = np; qg = nq;
        }
    }
}

// Second tuple output: the scalar C (=21) appended after x_patch.
__global__ void ape_tail(float* p, int n) {
    int i = blockIdx.x * blockDim.x + threadIdx.x;
    if (i < n) p[i] = 21.0f;
}

extern "C" void kernel_launch(void* const* d_in, const int* in_sizes, int n_in,
                              void* d_out, int out_size, void* d_ws, size_t ws_size,
                              hipStream_t stream)
{
    const float* x   = (const float*)d_in[0];
    const float* w1  = (const float*)d_in[1];
    const float* b1  = (const float*)d_in[2];
    const float* w2  = (const float*)d_in[3];
    const float* b2  = (const float*)d_in[4];
    const float* we0 = (const float*)d_in[5];
    const float* we1 = (const float*)d_in[6];
    const float* we2 = (const float*)d_in[7];
    float* out = (float*)d_out;
    int* preds = (int*)d_ws;                                // 43008 ints = 172 KB

    const long long NR = (long long)in_sizes[0] / MAX_PL;   // B*C*R = 43008

    ape_preds<<<(int)(NR / P_TILES), NTHREADS, 0, stream>>>(x, w1, b1, w2, b2, preds);

    const int nblocks = (int)(NR / G_TILES) * 2;            // 2688 half-blocks
    ape_embed<<<nblocks, NTHREADS, 0, stream>>>(x, preds, we0, we1, we2, out);

    const long long main_elems = NR * (long long)(TGT * D_MODEL);
    if ((long long)out_size > main_elems) {
        const int tail = (int)((long long)out_size - main_elems);
        ape_tail<<<(tail + 63) / 64, 64, 0, stream>>>(out + main_elems, tail);
    }
}